// Round 15
// baseline (420.451 us; speedup 1.0000x reference)
//
#include <hip/hip_runtime.h>
#include <hip/hip_fp16.h>
#include <type_traits>

// 2-layer GCN: h1 = relu(Anorm @ (x@w1) + b1); out = Anorm @ (h1@w2) + b2
// Atomic-free bucket-sort CSR; f16 tables; MFMA GEMMs.
// R14->R15:
//  (1) Layer-1 gather table + h1 stored SLICE-MAJOR [8][N][16dims] f16; agg1
//      runs one dim-slice per blockIdx&7 -> round-robin dispatch pins each
//      3.2MB slice to one XCD's L2 (R12 failed because sub-line splits don't
//      shrink LINE footprint; slice-major fixes the layout instead).
//      8 lanes/edge, 8 edges/wave-iter, butterfly reduce over edge slots.
//  (2) agg2 edge-pairing: half-waves process edge pairs (F=64 rows are only
//      32 dwords; un-paired, lanes 32-63 duplicated lanes 0-31's loads).

constexpr int B = 1024;       // dst-range buckets
constexpr int KB = 256;       // blocks in K1/K3

using half8 = __attribute__((ext_vector_type(8))) _Float16;
using f32x4 = __attribute__((ext_vector_type(4))) float;

// ---------------- edge dtype detect (int32 vs int64) ----------------
__global__ void detect_i64(const int* __restrict__ idx32, int* __restrict__ flag) {
    int v = idx32[2 * threadIdx.x + 1];
    unsigned long long b = __ballot(v != 0);
    if (threadIdx.x == 0) flag[0] = (b == 0ULL) ? 1 : 0;
}

__device__ __forceinline__ int load_idx(const void* edges, size_t i, int is64) {
    return is64 ? (int)((const long long*)edges)[i] : ((const int*)edges)[i];
}

__device__ __forceinline__ int clampN(int v, int N) {
    return ((unsigned)v < (unsigned)N) ? v : 0;
}

// ---- K1: per-block bucket histogram (1024 thr, x4 unroll). ----
__global__ __launch_bounds__(1024) void bucket_count(
    const void* __restrict__ edges, int E, int EPB, int NR,
    const int* __restrict__ flag, int* __restrict__ cnt, int N) {
    __shared__ int hist[B];
    int t = threadIdx.x, b = blockIdx.x;
    for (int k = t; k < B; k += 1024) hist[k] = 0;
    __syncthreads();
    int is64 = flag[0];
    int start = b * EPB, end = min(E, start + EPB);
    int j = start + t;
    for (; j + 3 * 1024 < end; j += 4 * 1024) {
        int d[4];
#pragma unroll
        for (int u = 0; u < 4; ++u)
            d[u] = clampN(load_idx(edges, (size_t)E + j + u * 1024, is64), N) / NR;
#pragma unroll
        for (int u = 0; u < 4; ++u) atomicAdd(&hist[d[u]], 1);
    }
    for (; j < end; j += 1024) {
        int d = clampN(load_idx(edges, (size_t)E + j, is64), N);
        atomicAdd(&hist[d / NR], 1);
    }
    __syncthreads();
    for (int k = t; k < B; k += 1024) cnt[(size_t)k * KB + b] = hist[k];
}

// ---------------- 3-kernel exclusive scan (M = B*KB elements) ----------------
__global__ void scan_partials(const int* __restrict__ in, int* __restrict__ partials, int M) {
    __shared__ int sm[256];
    int t = threadIdx.x, i = blockIdx.x * 256 + t;
    sm[t] = (i < M) ? in[i] : 0;
    __syncthreads();
    for (int off = 128; off > 0; off >>= 1) {
        if (t < off) sm[t] += sm[t + off];
        __syncthreads();
    }
    if (t == 0) partials[blockIdx.x] = sm[0];
}

__global__ void scan_scan(int* __restrict__ partials, int NB) {  // 1 block, 1024 thr
    __shared__ int sm[1024];
    int t = threadIdx.x;
    int v = (t < NB) ? partials[t] : 0;
    sm[t] = v; __syncthreads();
    for (int off = 1; off < 1024; off <<= 1) {
        int x = sm[t];
        int y = (t >= off) ? sm[t - off] : 0;
        __syncthreads();
        sm[t] = x + y;
        __syncthreads();
    }
    if (t < NB) partials[t] = (t == 0) ? 0 : sm[t - 1];  // exclusive
}

__global__ void scan_write(const int* __restrict__ in, const int* __restrict__ partials,
                           int* __restrict__ out, int M) {
    __shared__ int sm[256];
    int t = threadIdx.x, b = blockIdx.x, i = b * 256 + t;
    int v = (i < M) ? in[i] : 0;
    sm[t] = v; __syncthreads();
    for (int off = 1; off < 256; off <<= 1) {
        int x = sm[t];
        int y = (t >= off) ? sm[t - off] : 0;
        __syncthreads();
        sm[t] = x + y;
        __syncthreads();
    }
    if (i < M) out[i] = partials[b] + sm[t] - v;  // exclusive
}

// ---- K3: bucketed scatter (1024 thr, x4 unroll); rec = dlocal<<17 | src. ----
__global__ __launch_bounds__(1024) void bucket_scatter(
    const void* __restrict__ edges, int E, int EPB, int NR,
    const int* __restrict__ flag, const int* __restrict__ base,
    int* __restrict__ buck, int N) {
    __shared__ int cur[B];
    int t = threadIdx.x, b = blockIdx.x;
    for (int k = t; k < B; k += 1024) cur[k] = base[(size_t)k * KB + b];
    __syncthreads();
    int is64 = flag[0];
    int start = b * EPB, end = min(E, start + EPB);
    int j = start + t;
    for (; j + 3 * 1024 < end; j += 4 * 1024) {
        int s[4], bin[4], dl[4], pos[4];
#pragma unroll
        for (int u = 0; u < 4; ++u) {
            int jj = j + u * 1024;
            s[u] = clampN(load_idx(edges, (size_t)jj, is64), N);
            int d = clampN(load_idx(edges, (size_t)E + jj, is64), N);
            bin[u] = d / NR;
            dl[u] = d - bin[u] * NR;
        }
#pragma unroll
        for (int u = 0; u < 4; ++u) pos[u] = atomicAdd(&cur[bin[u]], 1);
#pragma unroll
        for (int u = 0; u < 4; ++u) buck[pos[u]] = (dl[u] << 17) | s[u];
    }
    for (; j < end; j += 1024) {
        int s = clampN(load_idx(edges, (size_t)j, is64), N);
        int d = clampN(load_idx(edges, (size_t)E + j, is64), N);
        int bin = d / NR;
        int dl = d - bin * NR;
        int pos = atomicAdd(&cur[bin], 1);
        buck[pos] = (dl << 17) | s;
    }
}

// ---- K4: per-bucket CSR (x4 unroll). LDS count + scan; writes CSR. ----
__global__ __launch_bounds__(256) void bucket_csr(
    const int* __restrict__ buck, const int* __restrict__ base, int E, int NR,
    float* __restrict__ dinv, int* __restrict__ rowptr,
    int* __restrict__ colx, int N) {
    __shared__ int hist[128];  // NR <= 128
    __shared__ int cnt0[128];
    __shared__ int cur[128];
    int t = threadIdx.x, b = blockIdx.x;
    if (b == 0 && t == 0) rowptr[N] = E;
    int d0 = b * NR;
    if (d0 >= N) return;
    int nr = min(NR, N - d0);
    int segbase = base[(size_t)b * KB];
    int segend = (b == B - 1) ? E : base[(size_t)(b + 1) * KB];

    if (t < 128) hist[t] = 0;
    __syncthreads();
    {
        int j = segbase + t;
        for (; j + 3 * 256 < segend; j += 4 * 256) {
            int v[4];
#pragma unroll
            for (int u = 0; u < 4; ++u) v[u] = buck[j + u * 256] >> 17;
#pragma unroll
            for (int u = 0; u < 4; ++u) atomicAdd(&hist[v[u]], 1);
        }
        for (; j < segend; j += 256) atomicAdd(&hist[buck[j] >> 17], 1);
    }
    __syncthreads();
    if (t < 128) cnt0[t] = hist[t];
    __syncthreads();
    for (int off = 1; off < 128; off <<= 1) {  // inclusive scan
        int v = 0;
        if (t < 128 && t >= off) v = hist[t - off];
        __syncthreads();
        if (t < 128) hist[t] += v;
        __syncthreads();
    }
    if (t < 128) {
        int ex = hist[t] - cnt0[t];  // exclusive
        cur[t] = ex;
        if (t < nr) {
            rowptr[d0 + t] = segbase + ex;
            dinv[d0 + t] = rsqrtf((float)(cnt0[t] + 1));  // +1 self-loop
        }
    }
    __syncthreads();
    {
        int j = segbase + t;
        for (; j + 3 * 256 < segend; j += 4 * 256) {
            int v[4], pos[4];
#pragma unroll
            for (int u = 0; u < 4; ++u) v[u] = buck[j + u * 256];
#pragma unroll
            for (int u = 0; u < 4; ++u) pos[u] = atomicAdd(&cur[v[u] >> 17], 1);
#pragma unroll
            for (int u = 0; u < 4; ++u) colx[segbase + pos[u]] = v[u] & 0x1FFFF;
        }
        for (; j < segend; j += 256) {
            int v = buck[j];
            int pos = segbase + atomicAdd(&cur[v >> 17], 1);
            colx[pos] = v & 0x1FFFF;
        }
    }
}

// ------- MFMA GEMM: G = f16( dinv .* (X @ W) ), K=128 fixed -------
// INS: X is f16 slice-major [8][M][16]. OUTS: G written slice-major.
template <typename XT, bool INS, bool OUTS>
__global__ __launch_bounds__(256) void gemm_mfma(
    const XT* __restrict__ X, const float* __restrict__ W,
    const float* __restrict__ dinv, __half* __restrict__ G, int M, int Ncols) {
    constexpr int BK = 128;
    constexpr int LDP = BK + 8;           // padded stride (f16)
    __shared__ _Float16 xA[64][LDP];      // [row][k]
    __shared__ _Float16 wB[64][LDP];      // [col][k]
    const int t = threadIdx.x;
    const int m0 = blockIdx.x * 64;
    const int c0 = blockIdx.y * 64;

    {
        int r = t & 63, kg = t >> 6;      // k range [kg*32, kg*32+32)
        int row = m0 + r; if (row >= M) row = M - 1;
        if constexpr (INS) {
            // slices 2kg, 2kg+1: 16 f16 (32B) each
            const uint4* s0 = (const uint4*)&X[((size_t)(2 * kg) * M + row) * 16];
            const uint4* s1 = (const uint4*)&X[((size_t)(2 * kg + 1) * M + row) * 16];
            uint4* dst = (uint4*)&xA[r][kg * 32];
            dst[0] = s0[0]; dst[1] = s0[1];
            dst[2] = s1[0]; dst[3] = s1[1];
        } else if constexpr (std::is_same<XT, __half>::value) {
            const uint4* src = (const uint4*)&X[(size_t)row * BK + kg * 32];
            uint4* dst = (uint4*)&xA[r][kg * 32];
#pragma unroll
            for (int q = 0; q < 4; ++q) dst[q] = src[q];
        } else {
            const XT* xr = &X[(size_t)row * BK + kg * 32];
#pragma unroll
            for (int c = 0; c < 32; c += 8) {
                float4 a = *(const float4*)&xr[c];
                float4 b = *(const float4*)&xr[c + 4];
                half8 h;
                h[0] = (_Float16)a.x; h[1] = (_Float16)a.y;
                h[2] = (_Float16)a.z; h[3] = (_Float16)a.w;
                h[4] = (_Float16)b.x; h[5] = (_Float16)b.y;
                h[6] = (_Float16)b.z; h[7] = (_Float16)b.w;
                *(half8*)&xA[r][kg * 32 + c] = h;
            }
        }
    }
    {
        int cg = t & 15, k0 = t >> 4;
#pragma unroll
        for (int kk = 0; kk < 8; ++kk) {
            int k = k0 + kk * 16;
            float4 wv = *(const float4*)&W[(size_t)k * Ncols + c0 + cg * 4];
            wB[cg * 4 + 0][k] = (_Float16)wv.x;
            wB[cg * 4 + 1][k] = (_Float16)wv.y;
            wB[cg * 4 + 2][k] = (_Float16)wv.z;
            wB[cg * 4 + 3][k] = (_Float16)wv.w;
        }
    }
    __syncthreads();

    const int wv = t >> 6;
    const int lane = t & 63;
    const int fr = lane & 15;
    const int kg8 = (lane >> 4) * 8;
    f32x4 acc0 = {0.f, 0.f, 0.f, 0.f};
    f32x4 acc1 = {0.f, 0.f, 0.f, 0.f};
    f32x4 acc2 = {0.f, 0.f, 0.f, 0.f};
    f32x4 acc3 = {0.f, 0.f, 0.f, 0.f};

#pragma unroll
    for (int ks = 0; ks < BK; ks += 32) {
        half8 af = *(half8*)&xA[wv * 16 + fr][ks + kg8];
        half8 b0 = *(half8*)&wB[0 * 16 + fr][ks + kg8];
        half8 b1 = *(half8*)&wB[1 * 16 + fr][ks + kg8];
        half8 b2 = *(half8*)&wB[2 * 16 + fr][ks + kg8];
        half8 b3 = *(half8*)&wB[3 * 16 + fr][ks + kg8];
        acc0 = __builtin_amdgcn_mfma_f32_16x16x32_f16(af, b0, acc0, 0, 0, 0);
        acc1 = __builtin_amdgcn_mfma_f32_16x16x32_f16(af, b1, acc1, 0, 0, 0);
        acc2 = __builtin_amdgcn_mfma_f32_16x16x32_f16(af, b2, acc2, 0, 0, 0);
        acc3 = __builtin_amdgcn_mfma_f32_16x16x32_f16(af, b3, acc3, 0, 0, 0);
    }

    int r0 = wv * 16 + (lane >> 4) * 4;
    float dv[4];
    bool ok[4];
#pragma unroll
    for (int i = 0; i < 4; ++i) {
        int row = m0 + r0 + i;
        ok[i] = row < M;
        dv[i] = ok[i] ? dinv[row] : 0.f;
    }
    const f32x4* accs[4] = {&acc0, &acc1, &acc2, &acc3};
#pragma unroll
    for (int fc = 0; fc < 4; ++fc) {
#pragma unroll
        for (int i = 0; i < 4; ++i) {
            if (ok[i]) {
                int row = m0 + r0 + i;
                __half h = __float2half((*accs[fc])[i] * dv[i]);
                if constexpr (OUTS) {
                    int sl = c0 / 16 + fc;
                    G[((size_t)sl * M + row) * 16 + fr] = h;
                } else {
                    G[(size_t)row * Ncols + c0 + fc * 16 + fr] = h;
                }
            }
        }
    }
}

// ------- agg1 sliced: slice = blockIdx&7 (XCD-pinned via round-robin) -------
// G, Out slice-major [8][N][16] f16. 8 lanes/edge (16 dims = 8 dwords),
// 8 edges per wave-iter; butterfly reduce over edge slots.
__global__ __launch_bounds__(256) void agg1_sliced(
    const __half* __restrict__ G, const int* __restrict__ rowptr,
    const int* __restrict__ colx, const float* __restrict__ dinv,
    const float* __restrict__ bias, __half* __restrict__ Out, int N) {
    int sl = blockIdx.x & 7;
    int nid = (int)((blockIdx.x >> 3) * 4) + (threadIdx.x >> 6);
    int lane = threadIdx.x & 63;
    if (nid >= N) return;
    int e8 = lane >> 3, d8 = lane & 7;
    int s = rowptr[nid], e = rowptr[nid + 1];
    int emain = s + ((e - s) & ~7);

    const unsigned* gp = (const unsigned*)G + (size_t)sl * N * 8;
    __half2 z = __floats2half2_rn(0.f, 0.f);
    unsigned su = gp[(size_t)nid * 8 + d8];        // self term (slot 0 only)
    __half2 acc = (e8 == 0) ? *(__half2*)&su : z;
    __half2 acc2 = z;

    int j = s;
    for (; j + 8 < emain; j += 16) {               // unroll x2 (16 edges)
        int c0i = colx[j + e8];
        int c1i = colx[j + 8 + e8];
        unsigned v0 = gp[(size_t)c0i * 8 + d8];
        unsigned v1 = gp[(size_t)c1i * 8 + d8];
        acc  = __hadd2(acc,  *(__half2*)&v0);
        acc2 = __hadd2(acc2, *(__half2*)&v1);
    }
    for (; j < emain; j += 8) {
        int ci = colx[j + e8];
        unsigned v = gp[(size_t)ci * 8 + d8];
        acc = __hadd2(acc, *(__half2*)&v);
    }
    if (emain < e) {                               // one masked 8-edge batch
        int jj = min(emain + e8, e - 1);
        int ci = clampN(colx[jj], N);
        unsigned v = gp[(size_t)ci * 8 + d8];
        __half2 w = (emain + e8 < e) ? __floats2half2_rn(1.f, 1.f) : z;
        acc = __hfma2(w, *(__half2*)&v, acc);
    }
    acc = __hadd2(acc, acc2);
#pragma unroll
    for (int off = 8; off < 64; off <<= 1) {       // butterfly over edge slots
        int bits = *(int*)&acc;
        int ob = __shfl_xor(bits, off, 64);
        acc = __hadd2(acc, *(__half2*)&ob);
    }
    if (e8 == 0) {                                 // lanes 0-7 write 32B/node
        float2 f = __half22float2(acc);
        float d = dinv[nid];
        float2 bv = *(const float2*)&bias[sl * 16 + d8 * 2];
        float ox = fmaf(d, f.x, bv.x);
        float oy = fmaf(d, f.y, bv.y);
        ox = fmaxf(ox, 0.f); oy = fmaxf(oy, 0.f);  // relu
        __half2 h = __floats2half2_rn(ox, oy);
        ((unsigned*)Out)[(size_t)sl * N * 8 + (size_t)nid * 8 + d8] = *(unsigned*)&h;
    }
}

// ------- agg2 paired (F=64): half-waves take edge pairs; f32 out -------
__global__ __launch_bounds__(256) void agg2_pair(
    const __half* __restrict__ G, const int* __restrict__ rowptr,
    const int* __restrict__ colx, const float* __restrict__ dinv,
    const float* __restrict__ bias, float* __restrict__ Out, int N) {
    constexpr int UNR = 16;
    int wid = (int)((blockIdx.x * 256 + threadIdx.x) >> 6);
    int lane = threadIdx.x & 63;
    if (wid >= N) return;
    int s = rowptr[wid], e = rowptr[wid + 1];
    int emain = s + ((e - s) & ~(UNR - 1));

    const unsigned* gp = (const unsigned*)G;       // row = 32 dwords
    int dw = lane & 31;
    int half = lane >> 5;

    __half2 z = __floats2half2_rn(0.f, 0.f);
    unsigned su = gp[(size_t)wid * 32 + dw];       // self (half 0 only)
    __half2 hacc = half ? z : *(__half2*)&su;
    __half2 hacc2 = z;

    for (int j = s; j < emain; j += UNR) {         // exact, unmasked
        int cl = colx[j + (lane & 15)];
        unsigned v[UNR / 2];
#pragma unroll
        for (int u = 0; u < UNR; u += 2) {
            int c0 = __builtin_amdgcn_readlane(cl, u);
            int c1 = __builtin_amdgcn_readlane(cl, u + 1);
            int cu = half ? c1 : c0;
            v[u / 2] = gp[(size_t)cu * 32 + dw];
        }
#pragma unroll
        for (int u = 0; u < UNR; u += 4) {
            hacc  = __hadd2(hacc,  *(__half2*)&v[u / 2]);
            hacc2 = __hadd2(hacc2, *(__half2*)&v[u / 2 + 1]);
        }
    }
    if (emain < e) {                               // one masked batch
        int cl = clampN(colx[min(emain + (lane & 15), e - 1)], N);
        const __half2 one2 = __floats2half2_rn(1.f, 1.f);
#pragma unroll
        for (int u = 0; u < UNR; u += 2) {
            int c0 = __builtin_amdgcn_readlane(cl, u);
            int c1 = __builtin_amdgcn_readlane(cl, u + 1);
            int cu = half ? c1 : c0;
            unsigned vv = gp[(size_t)cu * 32 + dw];
            int jj = emain + u + half;
            __half2 w = (jj < e) ? one2 : z;
            hacc = __hfma2(w, *(__half2*)&vv, hacc);
        }
    }

    hacc = __hadd2(hacc, hacc2);
    int bits = *(int*)&hacc;
    int other = __shfl_xor(bits, 32, 64);          // cross-half partial
    __half2 ho = *(__half2*)&other;
    float2 f1 = __half22float2(hacc);
    float2 f2 = __half22float2(ho);
    float ax = f1.x + f2.x, ay = f1.y + f2.y;

    if (half == 0) {
        float d = dinv[wid];
        float2 bv = *(const float2*)&bias[dw * 2];
        float2 o;
        o.x = fmaf(d, ax, bv.x);
        o.y = fmaf(d, ay, bv.y);
        *(float2*)&Out[(size_t)wid * 64 + dw * 2] = o;
    }
}

extern "C" void kernel_launch(void* const* d_in, const int* in_sizes, int n_in,
                              void* d_out, int out_size, void* d_ws, size_t ws_size,
                              hipStream_t stream) {
    const float* x  = (const float*)d_in[0];
    const void*  ei = d_in[1];
    const float* w1 = (const float*)d_in[2];
    const float* b1 = (const float*)d_in[3];
    const float* w2 = (const float*)d_in[4];
    const float* b2 = (const float*)d_in[5];
    float* out = (float*)d_out;

    const int N  = in_sizes[0] / 128;   // 100000
    const int E  = in_sizes[1] / 2;     // 3200000
    const int M  = B * KB;              // cnt matrix cells
    const int NR = (N + B - 1) / B;     // nodes per bucket (<=128)

    char* p = (char*)d_ws;
    auto carve = [&](size_t bytes) {
        void* r = (void*)p;
        p += (bytes + 255) & ~(size_t)255;
        return r;
    };
    int*    cnt      = (int*)carve((size_t)M * 4);
    int*    base     = (int*)carve((size_t)M * 4);
    int*    partials = (int*)carve(1024 * 4);
    int*    flag     = (int*)carve(256);
    int*    rowptr   = (int*)carve((size_t)(N + 1) * 4);
    float*  dinv     = (float*)carve((size_t)N * 4);
    int*    colx     = (int*)carve((size_t)E * 4);
    __half* g1       = (__half*)carve((size_t)N * 128 * 2);  // sliced [8][N][16]
    __half* a1       = (__half*)carve((size_t)N * 128 * 2);  // sliced [8][N][16]
    __half* g2       = g1;          // g1 dead after agg1; reuse ([N][64] fits)
    int*    buck     = (int*)a1;    // packed records dead before agg1 writes a1

    const int EPB = (E + KB - 1) / KB;  // edges per K1/K3 block
    const int NBS = M / 256;            // scan blocks (1024)

    detect_i64<<<1, 64, 0, stream>>>((const int*)ei, flag);
    bucket_count<<<KB, 1024, 0, stream>>>(ei, E, EPB, NR, flag, cnt, N);
    scan_partials<<<NBS, 256, 0, stream>>>(cnt, partials, M);
    scan_scan<<<1, 1024, 0, stream>>>(partials, NBS);
    scan_write<<<NBS, 256, 0, stream>>>(cnt, partials, base, M);
    bucket_scatter<<<KB, 1024, 0, stream>>>(ei, E, EPB, NR, flag, base, buck, N);
    bucket_csr<<<B, 256, 0, stream>>>(buck, base, E, NR, dinv, rowptr, colx, N);

    // layer 1: gemm -> sliced g1; agg1 sliced (slice = blockIdx&7) -> sliced a1
    dim3 grid1((N + 63) / 64, 2);
    gemm_mfma<float, false, true><<<grid1, 256, 0, stream>>>(x, w1, dinv, g1, N, 128);
    const int aggb1 = ((N + 3) / 4) * 8;
    agg1_sliced<<<aggb1, 256, 0, stream>>>(g1, rowptr, colx, dinv, b1, a1, N);

    // layer 2: gemm reads sliced a1, writes row-major g2; agg2 paired
    dim3 grid2((N + 63) / 64, 1);
    gemm_mfma<__half, true, false><<<grid2, 256, 0, stream>>>(a1, w2, dinv, g2, N, 64);
    agg2_pair<<<(N + 3) / 4, 256, 0, stream>>>(g2, rowptr, colx, dinv, b2, out, N);
}

// Round 16
// 283.315 us; speedup vs baseline: 1.4840x; 1.4840x over previous
//
#include <hip/hip_runtime.h>
#include <hip/hip_fp16.h>
#include <type_traits>

// 2-layer GCN: h1 = relu(Anorm @ (x@w1) + b1); out = Anorm @ (h1@w2) + b2
// Atomic-free bucket-sort CSR; f16 tables; MFMA GEMMs.
// R15->R16: REVERT agg1 to R14's two-pass row-major agg_split (R15's
// 8-slice agg1 validated XCD locality -- FETCH 360->67MB -- but 800k
// tiny waves paid ~2.5k-cycle fixed chains: 261us, net regression).
// KEEP agg2 edge-pairing (half-waves on edge pairs; F=64 rows are 32
// dwords so un-paired lanes 32-63 duplicated all loads).

constexpr int B = 1024;       // dst-range buckets
constexpr int KB = 256;       // blocks in K1/K3

using half8 = __attribute__((ext_vector_type(8))) _Float16;
using f32x4 = __attribute__((ext_vector_type(4))) float;

// ---------------- edge dtype detect (int32 vs int64) ----------------
__global__ void detect_i64(const int* __restrict__ idx32, int* __restrict__ flag) {
    int v = idx32[2 * threadIdx.x + 1];
    unsigned long long b = __ballot(v != 0);
    if (threadIdx.x == 0) flag[0] = (b == 0ULL) ? 1 : 0;
}

__device__ __forceinline__ int load_idx(const void* edges, size_t i, int is64) {
    return is64 ? (int)((const long long*)edges)[i] : ((const int*)edges)[i];
}

__device__ __forceinline__ int clampN(int v, int N) {
    return ((unsigned)v < (unsigned)N) ? v : 0;
}

// ---- K1: per-block bucket histogram (1024 thr, x4 unroll). ----
__global__ __launch_bounds__(1024) void bucket_count(
    const void* __restrict__ edges, int E, int EPB, int NR,
    const int* __restrict__ flag, int* __restrict__ cnt, int N) {
    __shared__ int hist[B];
    int t = threadIdx.x, b = blockIdx.x;
    for (int k = t; k < B; k += 1024) hist[k] = 0;
    __syncthreads();
    int is64 = flag[0];
    int start = b * EPB, end = min(E, start + EPB);
    int j = start + t;
    for (; j + 3 * 1024 < end; j += 4 * 1024) {
        int d[4];
#pragma unroll
        for (int u = 0; u < 4; ++u)
            d[u] = clampN(load_idx(edges, (size_t)E + j + u * 1024, is64), N) / NR;
#pragma unroll
        for (int u = 0; u < 4; ++u) atomicAdd(&hist[d[u]], 1);
    }
    for (; j < end; j += 1024) {
        int d = clampN(load_idx(edges, (size_t)E + j, is64), N);
        atomicAdd(&hist[d / NR], 1);
    }
    __syncthreads();
    for (int k = t; k < B; k += 1024) cnt[(size_t)k * KB + b] = hist[k];
}

// ---------------- 3-kernel exclusive scan (M = B*KB elements) ----------------
__global__ void scan_partials(const int* __restrict__ in, int* __restrict__ partials, int M) {
    __shared__ int sm[256];
    int t = threadIdx.x, i = blockIdx.x * 256 + t;
    sm[t] = (i < M) ? in[i] : 0;
    __syncthreads();
    for (int off = 128; off > 0; off >>= 1) {
        if (t < off) sm[t] += sm[t + off];
        __syncthreads();
    }
    if (t == 0) partials[blockIdx.x] = sm[0];
}

__global__ void scan_scan(int* __restrict__ partials, int NB) {  // 1 block, 1024 thr
    __shared__ int sm[1024];
    int t = threadIdx.x;
    int v = (t < NB) ? partials[t] : 0;
    sm[t] = v; __syncthreads();
    for (int off = 1; off < 1024; off <<= 1) {
        int x = sm[t];
        int y = (t >= off) ? sm[t - off] : 0;
        __syncthreads();
        sm[t] = x + y;
        __syncthreads();
    }
    if (t < NB) partials[t] = (t == 0) ? 0 : sm[t - 1];  // exclusive
}

__global__ void scan_write(const int* __restrict__ in, const int* __restrict__ partials,
                           int* __restrict__ out, int M) {
    __shared__ int sm[256];
    int t = threadIdx.x, b = blockIdx.x, i = b * 256 + t;
    int v = (i < M) ? in[i] : 0;
    sm[t] = v; __syncthreads();
    for (int off = 1; off < 256; off <<= 1) {
        int x = sm[t];
        int y = (t >= off) ? sm[t - off] : 0;
        __syncthreads();
        sm[t] = x + y;
        __syncthreads();
    }
    if (i < M) out[i] = partials[b] + sm[t] - v;  // exclusive
}

// ---- K3: bucketed scatter (1024 thr, x4 unroll); rec = dlocal<<17 | src. ----
__global__ __launch_bounds__(1024) void bucket_scatter(
    const void* __restrict__ edges, int E, int EPB, int NR,
    const int* __restrict__ flag, const int* __restrict__ base,
    int* __restrict__ buck, int N) {
    __shared__ int cur[B];
    int t = threadIdx.x, b = blockIdx.x;
    for (int k = t; k < B; k += 1024) cur[k] = base[(size_t)k * KB + b];
    __syncthreads();
    int is64 = flag[0];
    int start = b * EPB, end = min(E, start + EPB);
    int j = start + t;
    for (; j + 3 * 1024 < end; j += 4 * 1024) {
        int s[4], bin[4], dl[4], pos[4];
#pragma unroll
        for (int u = 0; u < 4; ++u) {
            int jj = j + u * 1024;
            s[u] = clampN(load_idx(edges, (size_t)jj, is64), N);
            int d = clampN(load_idx(edges, (size_t)E + jj, is64), N);
            bin[u] = d / NR;
            dl[u] = d - bin[u] * NR;
        }
#pragma unroll
        for (int u = 0; u < 4; ++u) pos[u] = atomicAdd(&cur[bin[u]], 1);
#pragma unroll
        for (int u = 0; u < 4; ++u) buck[pos[u]] = (dl[u] << 17) | s[u];
    }
    for (; j < end; j += 1024) {
        int s = clampN(load_idx(edges, (size_t)j, is64), N);
        int d = clampN(load_idx(edges, (size_t)E + j, is64), N);
        int bin = d / NR;
        int dl = d - bin * NR;
        int pos = atomicAdd(&cur[bin], 1);
        buck[pos] = (dl << 17) | s;
    }
}

// ---- K4: per-bucket CSR (x4 unroll). LDS count + scan; writes CSR. ----
__global__ __launch_bounds__(256) void bucket_csr(
    const int* __restrict__ buck, const int* __restrict__ base, int E, int NR,
    float* __restrict__ dinv, int* __restrict__ rowptr,
    int* __restrict__ colx, int N) {
    __shared__ int hist[128];  // NR <= 128
    __shared__ int cnt0[128];
    __shared__ int cur[128];
    int t = threadIdx.x, b = blockIdx.x;
    if (b == 0 && t == 0) rowptr[N] = E;
    int d0 = b * NR;
    if (d0 >= N) return;
    int nr = min(NR, N - d0);
    int segbase = base[(size_t)b * KB];
    int segend = (b == B - 1) ? E : base[(size_t)(b + 1) * KB];

    if (t < 128) hist[t] = 0;
    __syncthreads();
    {
        int j = segbase + t;
        for (; j + 3 * 256 < segend; j += 4 * 256) {
            int v[4];
#pragma unroll
            for (int u = 0; u < 4; ++u) v[u] = buck[j + u * 256] >> 17;
#pragma unroll
            for (int u = 0; u < 4; ++u) atomicAdd(&hist[v[u]], 1);
        }
        for (; j < segend; j += 256) atomicAdd(&hist[buck[j] >> 17], 1);
    }
    __syncthreads();
    if (t < 128) cnt0[t] = hist[t];
    __syncthreads();
    for (int off = 1; off < 128; off <<= 1) {  // inclusive scan
        int v = 0;
        if (t < 128 && t >= off) v = hist[t - off];
        __syncthreads();
        if (t < 128) hist[t] += v;
        __syncthreads();
    }
    if (t < 128) {
        int ex = hist[t] - cnt0[t];  // exclusive
        cur[t] = ex;
        if (t < nr) {
            rowptr[d0 + t] = segbase + ex;
            dinv[d0 + t] = rsqrtf((float)(cnt0[t] + 1));  // +1 self-loop
        }
    }
    __syncthreads();
    {
        int j = segbase + t;
        for (; j + 3 * 256 < segend; j += 4 * 256) {
            int v[4], pos[4];
#pragma unroll
            for (int u = 0; u < 4; ++u) v[u] = buck[j + u * 256];
#pragma unroll
            for (int u = 0; u < 4; ++u) pos[u] = atomicAdd(&cur[v[u] >> 17], 1);
#pragma unroll
            for (int u = 0; u < 4; ++u) colx[segbase + pos[u]] = v[u] & 0x1FFFF;
        }
        for (; j < segend; j += 256) {
            int v = buck[j];
            int pos = segbase + atomicAdd(&cur[v >> 17], 1);
            colx[pos] = v & 0x1FFFF;
        }
    }
}

// ------- MFMA GEMM: G = f16( dinv .* (X @ W) ), K=128; X f32 or f16 -------
template <typename XT>
__global__ __launch_bounds__(256) void gemm_mfma(
    const XT* __restrict__ X, const float* __restrict__ W,
    const float* __restrict__ dinv, __half* __restrict__ G, int M, int Ncols) {
    constexpr int BK = 128;
    constexpr int LDP = BK + 8;           // padded stride (f16)
    __shared__ _Float16 xA[64][LDP];      // [row][k]
    __shared__ _Float16 wB[64][LDP];      // [col][k]
    const int t = threadIdx.x;
    const int m0 = blockIdx.x * 64;
    const int c0 = blockIdx.y * 64;

    {
        int r = t & 63, kg = t >> 6;
        int row = m0 + r; if (row >= M) row = M - 1;
        const XT* xr = &X[(size_t)row * BK + kg * 32];
        if constexpr (std::is_same<XT, __half>::value) {
            const uint4* src = (const uint4*)xr;
            uint4* dst = (uint4*)&xA[r][kg * 32];
#pragma unroll
            for (int q = 0; q < 4; ++q) dst[q] = src[q];
        } else {
#pragma unroll
            for (int c = 0; c < 32; c += 8) {
                float4 a = *(const float4*)&xr[c];
                float4 b = *(const float4*)&xr[c + 4];
                half8 h;
                h[0] = (_Float16)a.x; h[1] = (_Float16)a.y;
                h[2] = (_Float16)a.z; h[3] = (_Float16)a.w;
                h[4] = (_Float16)b.x; h[5] = (_Float16)b.y;
                h[6] = (_Float16)b.z; h[7] = (_Float16)b.w;
                *(half8*)&xA[r][kg * 32 + c] = h;
            }
        }
    }
    {
        int cg = t & 15, k0 = t >> 4;
#pragma unroll
        for (int kk = 0; kk < 8; ++kk) {
            int k = k0 + kk * 16;
            float4 wv = *(const float4*)&W[(size_t)k * Ncols + c0 + cg * 4];
            wB[cg * 4 + 0][k] = (_Float16)wv.x;
            wB[cg * 4 + 1][k] = (_Float16)wv.y;
            wB[cg * 4 + 2][k] = (_Float16)wv.z;
            wB[cg * 4 + 3][k] = (_Float16)wv.w;
        }
    }
    __syncthreads();

    const int wv = t >> 6;
    const int lane = t & 63;
    const int fr = lane & 15;
    const int kg8 = (lane >> 4) * 8;
    f32x4 acc0 = {0.f, 0.f, 0.f, 0.f};
    f32x4 acc1 = {0.f, 0.f, 0.f, 0.f};
    f32x4 acc2 = {0.f, 0.f, 0.f, 0.f};
    f32x4 acc3 = {0.f, 0.f, 0.f, 0.f};

#pragma unroll
    for (int ks = 0; ks < BK; ks += 32) {
        half8 af = *(half8*)&xA[wv * 16 + fr][ks + kg8];
        half8 b0 = *(half8*)&wB[0 * 16 + fr][ks + kg8];
        half8 b1 = *(half8*)&wB[1 * 16 + fr][ks + kg8];
        half8 b2 = *(half8*)&wB[2 * 16 + fr][ks + kg8];
        half8 b3 = *(half8*)&wB[3 * 16 + fr][ks + kg8];
        acc0 = __builtin_amdgcn_mfma_f32_16x16x32_f16(af, b0, acc0, 0, 0, 0);
        acc1 = __builtin_amdgcn_mfma_f32_16x16x32_f16(af, b1, acc1, 0, 0, 0);
        acc2 = __builtin_amdgcn_mfma_f32_16x16x32_f16(af, b2, acc2, 0, 0, 0);
        acc3 = __builtin_amdgcn_mfma_f32_16x16x32_f16(af, b3, acc3, 0, 0, 0);
    }

    int r0 = wv * 16 + (lane >> 4) * 4;
    float dv[4];
    bool ok[4];
#pragma unroll
    for (int i = 0; i < 4; ++i) {
        int row = m0 + r0 + i;
        ok[i] = row < M;
        dv[i] = ok[i] ? dinv[row] : 0.f;
    }
    const f32x4* accs[4] = {&acc0, &acc1, &acc2, &acc3};
#pragma unroll
    for (int fc = 0; fc < 4; ++fc) {
        int col = c0 + fc * 16 + fr;
#pragma unroll
        for (int i = 0; i < 4; ++i) {
            if (ok[i]) {
                int row = m0 + r0 + i;
                G[(size_t)row * Ncols + col] = __float2half((*accs[fc])[i] * dv[i]);
            }
        }
    }
}

// ------- agg1 half-row pass: features [p*64, p*64+64), F=128 table -------
__global__ __launch_bounds__(256) void agg_split(
    const __half* __restrict__ G, const int* __restrict__ rowptr,
    const int* __restrict__ colx, const float* __restrict__ dinv,
    const float* __restrict__ bias, __half* __restrict__ Out, int N, int p) {
    constexpr int UNR = 16;
    int wid = (int)((blockIdx.x * 256 + threadIdx.x) >> 6);
    int lane = threadIdx.x & 63;
    if (wid >= N) return;
    int s = rowptr[wid], e = rowptr[wid + 1];
    int emain = s + ((e - s) & ~(UNR - 1));

    const unsigned* gp = (const unsigned*)G;       // row = 64 dwords
    int dw = p * 32 + (lane & 31);
    int half = lane >> 5;                          // 0 or 1

    __half2 z = __floats2half2_rn(0.f, 0.f);
    unsigned su = gp[(size_t)wid * 64 + dw];       // self term (count once)
    __half2 hacc = half ? z : *(__half2*)&su;
    __half2 hacc2 = z;

    for (int j = s; j < emain; j += UNR) {         // exact, unmasked
        int cl = colx[j + (lane & 15)];            // one coalesced load/batch
        unsigned v[UNR / 2];
#pragma unroll
        for (int u = 0; u < UNR; u += 2) {
            int c0 = __builtin_amdgcn_readlane(cl, u);
            int c1 = __builtin_amdgcn_readlane(cl, u + 1);
            int cu = half ? c1 : c0;
            v[u / 2] = gp[(size_t)cu * 64 + dw];
        }
#pragma unroll
        for (int u = 0; u < UNR; u += 4) {
            hacc  = __hadd2(hacc,  *(__half2*)&v[u / 2]);
            hacc2 = __hadd2(hacc2, *(__half2*)&v[u / 2 + 1]);
        }
    }
    if (emain < e) {                               // one masked batch
        int cl = clampN(colx[min(emain + (lane & 15), e - 1)], N);
        const __half2 one2 = __floats2half2_rn(1.f, 1.f);
#pragma unroll
        for (int u = 0; u < UNR; u += 2) {
            int c0 = __builtin_amdgcn_readlane(cl, u);
            int c1 = __builtin_amdgcn_readlane(cl, u + 1);
            int cu = half ? c1 : c0;
            unsigned vv = gp[(size_t)cu * 64 + dw];
            int jj = emain + u + half;
            __half2 w = (jj < e) ? one2 : z;
            hacc = __hfma2(w, *(__half2*)&vv, hacc);
        }
    }

    hacc = __hadd2(hacc, hacc2);
    int bits = *(int*)&hacc;
    int other = __shfl_xor(bits, 32, 64);          // cross-half partial
    __half2 ho = *(__half2*)&other;
    float2 f1 = __half22float2(hacc);
    float2 f2 = __half22float2(ho);
    float ax = f1.x + f2.x, ay = f1.y + f2.y;

    if (half == 0) {
        float d = dinv[wid];
        float2 bv = *(const float2*)&bias[dw * 2];
        float ox = fmaf(d, ax, bv.x);
        float oy = fmaf(d, ay, bv.y);
        ox = fmaxf(ox, 0.f); oy = fmaxf(oy, 0.f);  // relu (layer 1)
        __half2 h = __floats2half2_rn(ox, oy);
        ((unsigned*)Out)[(size_t)wid * 64 + dw] = *(unsigned*)&h;
    }
}

// ------- agg2 paired (F=64): half-waves take edge pairs; f32 out -------
__global__ __launch_bounds__(256) void agg2_pair(
    const __half* __restrict__ G, const int* __restrict__ rowptr,
    const int* __restrict__ colx, const float* __restrict__ dinv,
    const float* __restrict__ bias, float* __restrict__ Out, int N) {
    constexpr int UNR = 16;
    int wid = (int)((blockIdx.x * 256 + threadIdx.x) >> 6);
    int lane = threadIdx.x & 63;
    if (wid >= N) return;
    int s = rowptr[wid], e = rowptr[wid + 1];
    int emain = s + ((e - s) & ~(UNR - 1));

    const unsigned* gp = (const unsigned*)G;       // row = 32 dwords
    int dw = lane & 31;
    int half = lane >> 5;

    __half2 z = __floats2half2_rn(0.f, 0.f);
    unsigned su = gp[(size_t)wid * 32 + dw];       // self (half 0 only)
    __half2 hacc = half ? z : *(__half2*)&su;
    __half2 hacc2 = z;

    for (int j = s; j < emain; j += UNR) {         // exact, unmasked
        int cl = colx[j + (lane & 15)];
        unsigned v[UNR / 2];
#pragma unroll
        for (int u = 0; u < UNR; u += 2) {
            int c0 = __builtin_amdgcn_readlane(cl, u);
            int c1 = __builtin_amdgcn_readlane(cl, u + 1);
            int cu = half ? c1 : c0;
            v[u / 2] = gp[(size_t)cu * 32 + dw];
        }
#pragma unroll
        for (int u = 0; u < UNR; u += 4) {
            hacc  = __hadd2(hacc,  *(__half2*)&v[u / 2]);
            hacc2 = __hadd2(hacc2, *(__half2*)&v[u / 2 + 1]);
        }
    }
    if (emain < e) {                               // one masked batch
        int cl = clampN(colx[min(emain + (lane & 15), e - 1)], N);
        const __half2 one2 = __floats2half2_rn(1.f, 1.f);
#pragma unroll
        for (int u = 0; u < UNR; u += 2) {
            int c0 = __builtin_amdgcn_readlane(cl, u);
            int c1 = __builtin_amdgcn_readlane(cl, u + 1);
            int cu = half ? c1 : c0;
            unsigned vv = gp[(size_t)cu * 32 + dw];
            int jj = emain + u + half;
            __half2 w = (jj < e) ? one2 : z;
            hacc = __hfma2(w, *(__half2*)&vv, hacc);
        }
    }

    hacc = __hadd2(hacc, hacc2);
    int bits = *(int*)&hacc;
    int other = __shfl_xor(bits, 32, 64);          // cross-half partial
    __half2 ho = *(__half2*)&other;
    float2 f1 = __half22float2(hacc);
    float2 f2 = __half22float2(ho);
    float ax = f1.x + f2.x, ay = f1.y + f2.y;

    if (half == 0) {
        float d = dinv[wid];
        float2 bv = *(const float2*)&bias[dw * 2];
        float2 o;
        o.x = fmaf(d, ax, bv.x);
        o.y = fmaf(d, ay, bv.y);
        *(float2*)&Out[(size_t)wid * 64 + dw * 2] = o;
    }
}

extern "C" void kernel_launch(void* const* d_in, const int* in_sizes, int n_in,
                              void* d_out, int out_size, void* d_ws, size_t ws_size,
                              hipStream_t stream) {
    const float* x  = (const float*)d_in[0];
    const void*  ei = d_in[1];
    const float* w1 = (const float*)d_in[2];
    const float* b1 = (const float*)d_in[3];
    const float* w2 = (const float*)d_in[4];
    const float* b2 = (const float*)d_in[5];
    float* out = (float*)d_out;

    const int N  = in_sizes[0] / 128;   // 100000
    const int E  = in_sizes[1] / 2;     // 3200000
    const int M  = B * KB;              // cnt matrix cells
    const int NR = (N + B - 1) / B;     // nodes per bucket (<=128)

    char* p = (char*)d_ws;
    auto carve = [&](size_t bytes) {
        void* r = (void*)p;
        p += (bytes + 255) & ~(size_t)255;
        return r;
    };
    int*    cnt      = (int*)carve((size_t)M * 4);
    int*    base     = (int*)carve((size_t)M * 4);
    int*    partials = (int*)carve(1024 * 4);
    int*    flag     = (int*)carve(256);
    int*    rowptr   = (int*)carve((size_t)(N + 1) * 4);
    float*  dinv     = (float*)carve((size_t)N * 4);
    int*    colx     = (int*)carve((size_t)E * 4);
    __half* g1       = (__half*)carve((size_t)N * 128 * 2);  // f16 gather table
    __half* a1       = (__half*)carve((size_t)N * 128 * 2);  // f16 h1
    __half* g2       = g1;          // g1 dead after agg1; reuse
    int*    buck     = (int*)a1;    // packed records dead before agg1 writes a1

    const int EPB = (E + KB - 1) / KB;  // edges per K1/K3 block
    const int NBS = M / 256;            // scan blocks (1024)

    detect_i64<<<1, 64, 0, stream>>>((const int*)ei, flag);
    bucket_count<<<KB, 1024, 0, stream>>>(ei, E, EPB, NR, flag, cnt, N);
    scan_partials<<<NBS, 256, 0, stream>>>(cnt, partials, M);
    scan_scan<<<1, 1024, 0, stream>>>(partials, NBS);
    scan_write<<<NBS, 256, 0, stream>>>(cnt, partials, base, M);
    bucket_scatter<<<KB, 1024, 0, stream>>>(ei, E, EPB, NR, flag, base, buck, N);
    bucket_csr<<<B, 256, 0, stream>>>(buck, base, E, NR, dinv, rowptr, colx, N);

    // layer 1
    dim3 grid1((N + 63) / 64, 2);
    gemm_mfma<float><<<grid1, 256, 0, stream>>>(x, w1, dinv, g1, N, 128);
    const int aggb = (N + 3) / 4;
    agg_split<<<aggb, 256, 0, stream>>>(g1, rowptr, colx, dinv, b1, a1, N, 0);
    agg_split<<<aggb, 256, 0, stream>>>(g1, rowptr, colx, dinv, b1, a1, N, 1);

    // layer 2
    dim3 grid2((N + 63) / 64, 1);
    gemm_mfma<__half><<<grid2, 256, 0, stream>>>(a1, w2, dinv, g2, N, 64);
    agg2_pair<<<aggb, 256, 0, stream>>>(g2, rowptr, colx, dinv, b2, out, N);
}

// Round 17
// 275.595 us; speedup vs baseline: 1.5256x; 1.0280x over previous
//
#include <hip/hip_runtime.h>
#include <hip/hip_fp16.h>
#include <type_traits>

// 2-layer GCN: h1 = relu(Anorm @ (x@w1) + b1); out = Anorm @ (h1@w2) + b2
// Atomic-free bucket-sort CSR; f16 tables; MFMA GEMMs.
// R16->R17: agg1 reverted to R11's issue structure -- single pass over the
// full 256B row (64 lanes x 1 dword), readlane->SGPR addressing, 16 deep,
// NO half-wave pair select. R16's agg_split ran 2.7TB/s @ 66% VALU (pair
// cndmask starved VMEM issue); R11's structure measured 3.83TB/s @ 31%.
// agg2 stays paired (59us, best measured).

constexpr int B = 1024;       // dst-range buckets
constexpr int KB = 256;       // blocks in K1/K3

using half8 = __attribute__((ext_vector_type(8))) _Float16;
using f32x4 = __attribute__((ext_vector_type(4))) float;

// ---------------- edge dtype detect (int32 vs int64) ----------------
__global__ void detect_i64(const int* __restrict__ idx32, int* __restrict__ flag) {
    int v = idx32[2 * threadIdx.x + 1];
    unsigned long long b = __ballot(v != 0);
    if (threadIdx.x == 0) flag[0] = (b == 0ULL) ? 1 : 0;
}

__device__ __forceinline__ int load_idx(const void* edges, size_t i, int is64) {
    return is64 ? (int)((const long long*)edges)[i] : ((const int*)edges)[i];
}

__device__ __forceinline__ int clampN(int v, int N) {
    return ((unsigned)v < (unsigned)N) ? v : 0;
}

// ---- K1: per-block bucket histogram (1024 thr, x4 unroll). ----
__global__ __launch_bounds__(1024) void bucket_count(
    const void* __restrict__ edges, int E, int EPB, int NR,
    const int* __restrict__ flag, int* __restrict__ cnt, int N) {
    __shared__ int hist[B];
    int t = threadIdx.x, b = blockIdx.x;
    for (int k = t; k < B; k += 1024) hist[k] = 0;
    __syncthreads();
    int is64 = flag[0];
    int start = b * EPB, end = min(E, start + EPB);
    int j = start + t;
    for (; j + 3 * 1024 < end; j += 4 * 1024) {
        int d[4];
#pragma unroll
        for (int u = 0; u < 4; ++u)
            d[u] = clampN(load_idx(edges, (size_t)E + j + u * 1024, is64), N) / NR;
#pragma unroll
        for (int u = 0; u < 4; ++u) atomicAdd(&hist[d[u]], 1);
    }
    for (; j < end; j += 1024) {
        int d = clampN(load_idx(edges, (size_t)E + j, is64), N);
        atomicAdd(&hist[d / NR], 1);
    }
    __syncthreads();
    for (int k = t; k < B; k += 1024) cnt[(size_t)k * KB + b] = hist[k];
}

// ---------------- 3-kernel exclusive scan (M = B*KB elements) ----------------
__global__ void scan_partials(const int* __restrict__ in, int* __restrict__ partials, int M) {
    __shared__ int sm[256];
    int t = threadIdx.x, i = blockIdx.x * 256 + t;
    sm[t] = (i < M) ? in[i] : 0;
    __syncthreads();
    for (int off = 128; off > 0; off >>= 1) {
        if (t < off) sm[t] += sm[t + off];
        __syncthreads();
    }
    if (t == 0) partials[blockIdx.x] = sm[0];
}

__global__ void scan_scan(int* __restrict__ partials, int NB) {  // 1 block, 1024 thr
    __shared__ int sm[1024];
    int t = threadIdx.x;
    int v = (t < NB) ? partials[t] : 0;
    sm[t] = v; __syncthreads();
    for (int off = 1; off < 1024; off <<= 1) {
        int x = sm[t];
        int y = (t >= off) ? sm[t - off] : 0;
        __syncthreads();
        sm[t] = x + y;
        __syncthreads();
    }
    if (t < NB) partials[t] = (t == 0) ? 0 : sm[t - 1];  // exclusive
}

__global__ void scan_write(const int* __restrict__ in, const int* __restrict__ partials,
                           int* __restrict__ out, int M) {
    __shared__ int sm[256];
    int t = threadIdx.x, b = blockIdx.x, i = b * 256 + t;
    int v = (i < M) ? in[i] : 0;
    sm[t] = v; __syncthreads();
    for (int off = 1; off < 256; off <<= 1) {
        int x = sm[t];
        int y = (t >= off) ? sm[t - off] : 0;
        __syncthreads();
        sm[t] = x + y;
        __syncthreads();
    }
    if (i < M) out[i] = partials[b] + sm[t] - v;  // exclusive
}

// ---- K3: bucketed scatter (1024 thr, x4 unroll); rec = dlocal<<17 | src. ----
__global__ __launch_bounds__(1024) void bucket_scatter(
    const void* __restrict__ edges, int E, int EPB, int NR,
    const int* __restrict__ flag, const int* __restrict__ base,
    int* __restrict__ buck, int N) {
    __shared__ int cur[B];
    int t = threadIdx.x, b = blockIdx.x;
    for (int k = t; k < B; k += 1024) cur[k] = base[(size_t)k * KB + b];
    __syncthreads();
    int is64 = flag[0];
    int start = b * EPB, end = min(E, start + EPB);
    int j = start + t;
    for (; j + 3 * 1024 < end; j += 4 * 1024) {
        int s[4], bin[4], dl[4], pos[4];
#pragma unroll
        for (int u = 0; u < 4; ++u) {
            int jj = j + u * 1024;
            s[u] = clampN(load_idx(edges, (size_t)jj, is64), N);
            int d = clampN(load_idx(edges, (size_t)E + jj, is64), N);
            bin[u] = d / NR;
            dl[u] = d - bin[u] * NR;
        }
#pragma unroll
        for (int u = 0; u < 4; ++u) pos[u] = atomicAdd(&cur[bin[u]], 1);
#pragma unroll
        for (int u = 0; u < 4; ++u) buck[pos[u]] = (dl[u] << 17) | s[u];
    }
    for (; j < end; j += 1024) {
        int s = clampN(load_idx(edges, (size_t)j, is64), N);
        int d = clampN(load_idx(edges, (size_t)E + j, is64), N);
        int bin = d / NR;
        int dl = d - bin * NR;
        int pos = atomicAdd(&cur[bin], 1);
        buck[pos] = (dl << 17) | s;
    }
}

// ---- K4: per-bucket CSR (x4 unroll). LDS count + scan; writes CSR. ----
__global__ __launch_bounds__(256) void bucket_csr(
    const int* __restrict__ buck, const int* __restrict__ base, int E, int NR,
    float* __restrict__ dinv, int* __restrict__ rowptr,
    int* __restrict__ colx, int N) {
    __shared__ int hist[128];  // NR <= 128
    __shared__ int cnt0[128];
    __shared__ int cur[128];
    int t = threadIdx.x, b = blockIdx.x;
    if (b == 0 && t == 0) rowptr[N] = E;
    int d0 = b * NR;
    if (d0 >= N) return;
    int nr = min(NR, N - d0);
    int segbase = base[(size_t)b * KB];
    int segend = (b == B - 1) ? E : base[(size_t)(b + 1) * KB];

    if (t < 128) hist[t] = 0;
    __syncthreads();
    {
        int j = segbase + t;
        for (; j + 3 * 256 < segend; j += 4 * 256) {
            int v[4];
#pragma unroll
            for (int u = 0; u < 4; ++u) v[u] = buck[j + u * 256] >> 17;
#pragma unroll
            for (int u = 0; u < 4; ++u) atomicAdd(&hist[v[u]], 1);
        }
        for (; j < segend; j += 256) atomicAdd(&hist[buck[j] >> 17], 1);
    }
    __syncthreads();
    if (t < 128) cnt0[t] = hist[t];
    __syncthreads();
    for (int off = 1; off < 128; off <<= 1) {  // inclusive scan
        int v = 0;
        if (t < 128 && t >= off) v = hist[t - off];
        __syncthreads();
        if (t < 128) hist[t] += v;
        __syncthreads();
    }
    if (t < 128) {
        int ex = hist[t] - cnt0[t];  // exclusive
        cur[t] = ex;
        if (t < nr) {
            rowptr[d0 + t] = segbase + ex;
            dinv[d0 + t] = rsqrtf((float)(cnt0[t] + 1));  // +1 self-loop
        }
    }
    __syncthreads();
    {
        int j = segbase + t;
        for (; j + 3 * 256 < segend; j += 4 * 256) {
            int v[4], pos[4];
#pragma unroll
            for (int u = 0; u < 4; ++u) v[u] = buck[j + u * 256];
#pragma unroll
            for (int u = 0; u < 4; ++u) pos[u] = atomicAdd(&cur[v[u] >> 17], 1);
#pragma unroll
            for (int u = 0; u < 4; ++u) colx[segbase + pos[u]] = v[u] & 0x1FFFF;
        }
        for (; j < segend; j += 256) {
            int v = buck[j];
            int pos = segbase + atomicAdd(&cur[v >> 17], 1);
            colx[pos] = v & 0x1FFFF;
        }
    }
}

// ------- MFMA GEMM: G = f16( dinv .* (X @ W) ), K=128; X f32 or f16 -------
template <typename XT>
__global__ __launch_bounds__(256) void gemm_mfma(
    const XT* __restrict__ X, const float* __restrict__ W,
    const float* __restrict__ dinv, __half* __restrict__ G, int M, int Ncols) {
    constexpr int BK = 128;
    constexpr int LDP = BK + 8;           // padded stride (f16)
    __shared__ _Float16 xA[64][LDP];      // [row][k]
    __shared__ _Float16 wB[64][LDP];      // [col][k]
    const int t = threadIdx.x;
    const int m0 = blockIdx.x * 64;
    const int c0 = blockIdx.y * 64;

    {
        int r = t & 63, kg = t >> 6;
        int row = m0 + r; if (row >= M) row = M - 1;
        const XT* xr = &X[(size_t)row * BK + kg * 32];
        if constexpr (std::is_same<XT, __half>::value) {
            const uint4* src = (const uint4*)xr;
            uint4* dst = (uint4*)&xA[r][kg * 32];
#pragma unroll
            for (int q = 0; q < 4; ++q) dst[q] = src[q];
        } else {
#pragma unroll
            for (int c = 0; c < 32; c += 8) {
                float4 a = *(const float4*)&xr[c];
                float4 b = *(const float4*)&xr[c + 4];
                half8 h;
                h[0] = (_Float16)a.x; h[1] = (_Float16)a.y;
                h[2] = (_Float16)a.z; h[3] = (_Float16)a.w;
                h[4] = (_Float16)b.x; h[5] = (_Float16)b.y;
                h[6] = (_Float16)b.z; h[7] = (_Float16)b.w;
                *(half8*)&xA[r][kg * 32 + c] = h;
            }
        }
    }
    {
        int cg = t & 15, k0 = t >> 4;
#pragma unroll
        for (int kk = 0; kk < 8; ++kk) {
            int k = k0 + kk * 16;
            float4 wv = *(const float4*)&W[(size_t)k * Ncols + c0 + cg * 4];
            wB[cg * 4 + 0][k] = (_Float16)wv.x;
            wB[cg * 4 + 1][k] = (_Float16)wv.y;
            wB[cg * 4 + 2][k] = (_Float16)wv.z;
            wB[cg * 4 + 3][k] = (_Float16)wv.w;
        }
    }
    __syncthreads();

    const int wv = t >> 6;
    const int lane = t & 63;
    const int fr = lane & 15;
    const int kg8 = (lane >> 4) * 8;
    f32x4 acc0 = {0.f, 0.f, 0.f, 0.f};
    f32x4 acc1 = {0.f, 0.f, 0.f, 0.f};
    f32x4 acc2 = {0.f, 0.f, 0.f, 0.f};
    f32x4 acc3 = {0.f, 0.f, 0.f, 0.f};

#pragma unroll
    for (int ks = 0; ks < BK; ks += 32) {
        half8 af = *(half8*)&xA[wv * 16 + fr][ks + kg8];
        half8 b0 = *(half8*)&wB[0 * 16 + fr][ks + kg8];
        half8 b1 = *(half8*)&wB[1 * 16 + fr][ks + kg8];
        half8 b2 = *(half8*)&wB[2 * 16 + fr][ks + kg8];
        half8 b3 = *(half8*)&wB[3 * 16 + fr][ks + kg8];
        acc0 = __builtin_amdgcn_mfma_f32_16x16x32_f16(af, b0, acc0, 0, 0, 0);
        acc1 = __builtin_amdgcn_mfma_f32_16x16x32_f16(af, b1, acc1, 0, 0, 0);
        acc2 = __builtin_amdgcn_mfma_f32_16x16x32_f16(af, b2, acc2, 0, 0, 0);
        acc3 = __builtin_amdgcn_mfma_f32_16x16x32_f16(af, b3, acc3, 0, 0, 0);
    }

    int r0 = wv * 16 + (lane >> 4) * 4;
    float dv[4];
    bool ok[4];
#pragma unroll
    for (int i = 0; i < 4; ++i) {
        int row = m0 + r0 + i;
        ok[i] = row < M;
        dv[i] = ok[i] ? dinv[row] : 0.f;
    }
    const f32x4* accs[4] = {&acc0, &acc1, &acc2, &acc3};
#pragma unroll
    for (int fc = 0; fc < 4; ++fc) {
        int col = c0 + fc * 16 + fr;
#pragma unroll
        for (int i = 0; i < 4; ++i) {
            if (ok[i]) {
                int row = m0 + r0 + i;
                G[(size_t)row * Ncols + col] = __float2half((*accs[fc])[i] * dv[i]);
            }
        }
    }
}

// ------- agg1 (F=128, R11 structure): single pass, 64 lanes x 1 dword -------
// f16 table [N][128]; readlane -> SGPR row index; 16 outstanding gathers;
// unmasked main loop + one masked tail batch; f16 output row-major [N][128].
__global__ __launch_bounds__(256) void agg1_full(
    const __half* __restrict__ G, const int* __restrict__ rowptr,
    const int* __restrict__ colx, const float* __restrict__ dinv,
    const float* __restrict__ bias, __half* __restrict__ Out, int N) {
    constexpr int UNR = 16;
    int wid = (int)((blockIdx.x * 256 + threadIdx.x) >> 6);
    int lane = threadIdx.x & 63;
    if (wid >= N) return;
    int s = rowptr[wid], e = rowptr[wid + 1];
    int emain = s + ((e - s) & ~(UNR - 1));

    const unsigned* gp = (const unsigned*)G;          // row = 64 dwords
    unsigned su = gp[((size_t)wid << 6) + lane];      // self term
    __half2 hacc = *(__half2*)&su;
    __half2 hacc2 = __floats2half2_rn(0.f, 0.f);

    for (int j = s; j < emain; j += UNR) {            // exact, unmasked
        int cl = colx[j + (lane & 15)];               // one coalesced load/batch
        unsigned v[UNR];
#pragma unroll
        for (int u = 0; u < UNR; ++u) {
            int cu = __builtin_amdgcn_readlane(cl, u);    // SGPR index
            v[u] = gp[((size_t)cu << 6) + lane];
        }
#pragma unroll
        for (int u = 0; u < UNR; u += 2) {
            hacc  = __hadd2(hacc,  *(__half2*)&v[u]);
            hacc2 = __hadd2(hacc2, *(__half2*)&v[u + 1]);
        }
    }
    if (emain < e) {                                  // one masked batch
        int cl = clampN(colx[min(emain + (lane & 15), e - 1)], N);
        const __half2 one2 = __floats2half2_rn(1.f, 1.f);
        const __half2 zero2 = __floats2half2_rn(0.f, 0.f);
#pragma unroll
        for (int u = 0; u < UNR; ++u) {
            int cu = __builtin_amdgcn_readlane(cl, u);
            unsigned vv = gp[((size_t)cu << 6) + lane];
            __half2 w = (emain + u < e) ? one2 : zero2;
            hacc = __hfma2(w, *(__half2*)&vv, hacc);
        }
    }

    float2 f1 = __half22float2(hacc);
    float2 f2 = __half22float2(hacc2);
    float ax = f1.x + f2.x, ay = f1.y + f2.y;
    float d = dinv[wid];
    float2 bv = *(const float2*)&bias[lane * 2];
    float ox = fmaf(d, ax, bv.x);
    float oy = fmaf(d, ay, bv.y);
    ox = fmaxf(ox, 0.f); oy = fmaxf(oy, 0.f);         // relu (layer 1)
    __half2 h = __floats2half2_rn(ox, oy);
    ((unsigned*)Out)[((size_t)wid << 6) + lane] = *(unsigned*)&h;
}

// ------- agg2 paired (F=64): half-waves take edge pairs; f32 out -------
__global__ __launch_bounds__(256) void agg2_pair(
    const __half* __restrict__ G, const int* __restrict__ rowptr,
    const int* __restrict__ colx, const float* __restrict__ dinv,
    const float* __restrict__ bias, float* __restrict__ Out, int N) {
    constexpr int UNR = 16;
    int wid = (int)((blockIdx.x * 256 + threadIdx.x) >> 6);
    int lane = threadIdx.x & 63;
    if (wid >= N) return;
    int s = rowptr[wid], e = rowptr[wid + 1];
    int emain = s + ((e - s) & ~(UNR - 1));

    const unsigned* gp = (const unsigned*)G;       // row = 32 dwords
    int dw = lane & 31;
    int half = lane >> 5;

    __half2 z = __floats2half2_rn(0.f, 0.f);
    unsigned su = gp[(size_t)wid * 32 + dw];       // self (half 0 only)
    __half2 hacc = half ? z : *(__half2*)&su;
    __half2 hacc2 = z;

    for (int j = s; j < emain; j += UNR) {         // exact, unmasked
        int cl = colx[j + (lane & 15)];
        unsigned v[UNR / 2];
#pragma unroll
        for (int u = 0; u < UNR; u += 2) {
            int c0 = __builtin_amdgcn_readlane(cl, u);
            int c1 = __builtin_amdgcn_readlane(cl, u + 1);
            int cu = half ? c1 : c0;
            v[u / 2] = gp[(size_t)cu * 32 + dw];
        }
#pragma unroll
        for (int u = 0; u < UNR; u += 4) {
            hacc  = __hadd2(hacc,  *(__half2*)&v[u / 2]);
            hacc2 = __hadd2(hacc2, *(__half2*)&v[u / 2 + 1]);
        }
    }
    if (emain < e) {                               // one masked batch
        int cl = clampN(colx[min(emain + (lane & 15), e - 1)], N);
        const __half2 one2 = __floats2half2_rn(1.f, 1.f);
#pragma unroll
        for (int u = 0; u < UNR; u += 2) {
            int c0 = __builtin_amdgcn_readlane(cl, u);
            int c1 = __builtin_amdgcn_readlane(cl, u + 1);
            int cu = half ? c1 : c0;
            unsigned vv = gp[(size_t)cu * 32 + dw];
            int jj = emain + u + half;
            __half2 w = (jj < e) ? one2 : z;
            hacc = __hfma2(w, *(__half2*)&vv, hacc);
        }
    }

    hacc = __hadd2(hacc, hacc2);
    int bits = *(int*)&hacc;
    int other = __shfl_xor(bits, 32, 64);          // cross-half partial
    __half2 ho = *(__half2*)&other;
    float2 f1 = __half22float2(hacc);
    float2 f2 = __half22float2(ho);
    float ax = f1.x + f2.x, ay = f1.y + f2.y;

    if (half == 0) {
        float d = dinv[wid];
        float2 bv = *(const float2*)&bias[dw * 2];
        float2 o;
        o.x = fmaf(d, ax, bv.x);
        o.y = fmaf(d, ay, bv.y);
        *(float2*)&Out[(size_t)wid * 64 + dw * 2] = o;
    }
}

extern "C" void kernel_launch(void* const* d_in, const int* in_sizes, int n_in,
                              void* d_out, int out_size, void* d_ws, size_t ws_size,
                              hipStream_t stream) {
    const float* x  = (const float*)d_in[0];
    const void*  ei = d_in[1];
    const float* w1 = (const float*)d_in[2];
    const float* b1 = (const float*)d_in[3];
    const float* w2 = (const float*)d_in[4];
    const float* b2 = (const float*)d_in[5];
    float* out = (float*)d_out;

    const int N  = in_sizes[0] / 128;   // 100000
    const int E  = in_sizes[1] / 2;     // 3200000
    const int M  = B * KB;              // cnt matrix cells
    const int NR = (N + B - 1) / B;     // nodes per bucket (<=128)

    char* p = (char*)d_ws;
    auto carve = [&](size_t bytes) {
        void* r = (void*)p;
        p += (bytes + 255) & ~(size_t)255;
        return r;
    };
    int*    cnt      = (int*)carve((size_t)M * 4);
    int*    base     = (int*)carve((size_t)M * 4);
    int*    partials = (int*)carve(1024 * 4);
    int*    flag     = (int*)carve(256);
    int*    rowptr   = (int*)carve((size_t)(N + 1) * 4);
    float*  dinv     = (float*)carve((size_t)N * 4);
    int*    colx     = (int*)carve((size_t)E * 4);
    __half* g1       = (__half*)carve((size_t)N * 128 * 2);  // f16 gather table
    __half* a1       = (__half*)carve((size_t)N * 128 * 2);  // f16 h1
    __half* g2       = g1;          // g1 dead after agg1; reuse
    int*    buck     = (int*)a1;    // packed records dead before agg1 writes a1

    const int EPB = (E + KB - 1) / KB;  // edges per K1/K3 block
    const int NBS = M / 256;            // scan blocks (1024)

    detect_i64<<<1, 64, 0, stream>>>((const int*)ei, flag);
    bucket_count<<<KB, 1024, 0, stream>>>(ei, E, EPB, NR, flag, cnt, N);
    scan_partials<<<NBS, 256, 0, stream>>>(cnt, partials, M);
    scan_scan<<<1, 1024, 0, stream>>>(partials, NBS);
    scan_write<<<NBS, 256, 0, stream>>>(cnt, partials, base, M);
    bucket_scatter<<<KB, 1024, 0, stream>>>(ei, E, EPB, NR, flag, base, buck, N);
    bucket_csr<<<B, 256, 0, stream>>>(buck, base, E, NR, dinv, rowptr, colx, N);

    // layer 1
    dim3 grid1((N + 63) / 64, 2);
    gemm_mfma<float><<<grid1, 256, 0, stream>>>(x, w1, dinv, g1, N, 128);
    const int aggb = (N + 3) / 4;
    agg1_full<<<aggb, 256, 0, stream>>>(g1, rowptr, colx, dinv, b1, a1, N);

    // layer 2
    dim3 grid2((N + 63) / 64, 1);
    gemm_mfma<__half><<<grid2, 256, 0, stream>>>(a1, w2, dinv, g2, N, 64);
    agg2_pair<<<aggb, 256, 0, stream>>>(g2, rowptr, colx, dinv, b2, out, N);
}

// Round 18
// 272.097 us; speedup vs baseline: 1.5452x; 1.0129x over previous
//
#include <hip/hip_runtime.h>
#include <hip/hip_fp16.h>
#include <type_traits>

// 2-layer GCN: h1 = relu(Anorm @ (x@w1) + b1); out = Anorm @ (h1@w2) + b2
// Atomic-free bucket-sort CSR; f16 tables; MFMA GEMMs; R11/R17 agg issue
// structure (readlane->SGPR gathers, 16 deep, full 256B rows for layer 1).
// R17->R18: detect_i64 kernel removed -- int32/int64 edge dtype detection
// inlined (wave-0 ballot + LDS broadcast) into bucket_count/bucket_scatter.
// One fewer dispatch; removes the flag-load dependency stall at the head
// of both edge-reading kernels. Everything else unchanged from R17.

constexpr int B = 1024;       // dst-range buckets
constexpr int KB = 256;       // blocks in K1/K3

using half8 = __attribute__((ext_vector_type(8))) _Float16;
using f32x4 = __attribute__((ext_vector_type(4))) float;

__device__ __forceinline__ int load_idx(const void* edges, size_t i, int is64) {
    return is64 ? (int)((const long long*)edges)[i] : ((const int*)edges)[i];
}

__device__ __forceinline__ int clampN(int v, int N) {
    return ((unsigned)v < (unsigned)N) ? v : 0;
}

// Wave-0 detects int64 edges (odd dwords of first 64 entries all zero),
// broadcasts via LDS. Call at kernel head; returns block-uniform flag.
__device__ __forceinline__ int detect_is64_block(const void* edges, int* sm) {
    int t = threadIdx.x;
    if (t < 64) {
        int v = ((const int*)edges)[2 * t + 1];
        unsigned long long b = __ballot(v != 0);
        if (t == 0) *sm = (b == 0ULL) ? 1 : 0;
    }
    __syncthreads();
    return *sm;
}

// ---- K1: per-block bucket histogram (1024 thr, x4 unroll). ----
__global__ __launch_bounds__(1024) void bucket_count(
    const void* __restrict__ edges, int E, int EPB, int NR,
    int* __restrict__ cnt, int N) {
    __shared__ int hist[B];
    __shared__ int s_is64;
    int t = threadIdx.x, b = blockIdx.x;
    int is64 = detect_is64_block(edges, &s_is64);
    for (int k = t; k < B; k += 1024) hist[k] = 0;
    __syncthreads();
    int start = b * EPB, end = min(E, start + EPB);
    int j = start + t;
    for (; j + 3 * 1024 < end; j += 4 * 1024) {
        int d[4];
#pragma unroll
        for (int u = 0; u < 4; ++u)
            d[u] = clampN(load_idx(edges, (size_t)E + j + u * 1024, is64), N) / NR;
#pragma unroll
        for (int u = 0; u < 4; ++u) atomicAdd(&hist[d[u]], 1);
    }
    for (; j < end; j += 1024) {
        int d = clampN(load_idx(edges, (size_t)E + j, is64), N);
        atomicAdd(&hist[d / NR], 1);
    }
    __syncthreads();
    for (int k = t; k < B; k += 1024) cnt[(size_t)k * KB + b] = hist[k];
}

// ---------------- 3-kernel exclusive scan (M = B*KB elements) ----------------
__global__ void scan_partials(const int* __restrict__ in, int* __restrict__ partials, int M) {
    __shared__ int sm[256];
    int t = threadIdx.x, i = blockIdx.x * 256 + t;
    sm[t] = (i < M) ? in[i] : 0;
    __syncthreads();
    for (int off = 128; off > 0; off >>= 1) {
        if (t < off) sm[t] += sm[t + off];
        __syncthreads();
    }
    if (t == 0) partials[blockIdx.x] = sm[0];
}

__global__ void scan_scan(int* __restrict__ partials, int NB) {  // 1 block, 1024 thr
    __shared__ int sm[1024];
    int t = threadIdx.x;
    int v = (t < NB) ? partials[t] : 0;
    sm[t] = v; __syncthreads();
    for (int off = 1; off < 1024; off <<= 1) {
        int x = sm[t];
        int y = (t >= off) ? sm[t - off] : 0;
        __syncthreads();
        sm[t] = x + y;
        __syncthreads();
    }
    if (t < NB) partials[t] = (t == 0) ? 0 : sm[t - 1];  // exclusive
}

__global__ void scan_write(const int* __restrict__ in, const int* __restrict__ partials,
                           int* __restrict__ out, int M) {
    __shared__ int sm[256];
    int t = threadIdx.x, b = blockIdx.x, i = b * 256 + t;
    int v = (i < M) ? in[i] : 0;
    sm[t] = v; __syncthreads();
    for (int off = 1; off < 256; off <<= 1) {
        int x = sm[t];
        int y = (t >= off) ? sm[t - off] : 0;
        __syncthreads();
        sm[t] = x + y;
        __syncthreads();
    }
    if (i < M) out[i] = partials[b] + sm[t] - v;  // exclusive
}

// ---- K3: bucketed scatter (1024 thr, x4 unroll); rec = dlocal<<17 | src. ----
__global__ __launch_bounds__(1024) void bucket_scatter(
    const void* __restrict__ edges, int E, int EPB, int NR,
    const int* __restrict__ base, int* __restrict__ buck, int N) {
    __shared__ int cur[B];
    __shared__ int s_is64;
    int t = threadIdx.x, b = blockIdx.x;
    int is64 = detect_is64_block(edges, &s_is64);
    for (int k = t; k < B; k += 1024) cur[k] = base[(size_t)k * KB + b];
    __syncthreads();
    int start = b * EPB, end = min(E, start + EPB);
    int j = start + t;
    for (; j + 3 * 1024 < end; j += 4 * 1024) {
        int s[4], bin[4], dl[4], pos[4];
#pragma unroll
        for (int u = 0; u < 4; ++u) {
            int jj = j + u * 1024;
            s[u] = clampN(load_idx(edges, (size_t)jj, is64), N);
            int d = clampN(load_idx(edges, (size_t)E + jj, is64), N);
            bin[u] = d / NR;
            dl[u] = d - bin[u] * NR;
        }
#pragma unroll
        for (int u = 0; u < 4; ++u) pos[u] = atomicAdd(&cur[bin[u]], 1);
#pragma unroll
        for (int u = 0; u < 4; ++u) buck[pos[u]] = (dl[u] << 17) | s[u];
    }
    for (; j < end; j += 1024) {
        int s = clampN(load_idx(edges, (size_t)j, is64), N);
        int d = clampN(load_idx(edges, (size_t)E + j, is64), N);
        int bin = d / NR;
        int dl = d - bin * NR;
        int pos = atomicAdd(&cur[bin], 1);
        buck[pos] = (dl << 17) | s;
    }
}

// ---- K4: per-bucket CSR (x4 unroll). LDS count + scan; writes CSR. ----
__global__ __launch_bounds__(256) void bucket_csr(
    const int* __restrict__ buck, const int* __restrict__ base, int E, int NR,
    float* __restrict__ dinv, int* __restrict__ rowptr,
    int* __restrict__ colx, int N) {
    __shared__ int hist[128];  // NR <= 128
    __shared__ int cnt0[128];
    __shared__ int cur[128];
    int t = threadIdx.x, b = blockIdx.x;
    if (b == 0 && t == 0) rowptr[N] = E;
    int d0 = b * NR;
    if (d0 >= N) return;
    int nr = min(NR, N - d0);
    int segbase = base[(size_t)b * KB];
    int segend = (b == B - 1) ? E : base[(size_t)(b + 1) * KB];

    if (t < 128) hist[t] = 0;
    __syncthreads();
    {
        int j = segbase + t;
        for (; j + 3 * 256 < segend; j += 4 * 256) {
            int v[4];
#pragma unroll
            for (int u = 0; u < 4; ++u) v[u] = buck[j + u * 256] >> 17;
#pragma unroll
            for (int u = 0; u < 4; ++u) atomicAdd(&hist[v[u]], 1);
        }
        for (; j < segend; j += 256) atomicAdd(&hist[buck[j] >> 17], 1);
    }
    __syncthreads();
    if (t < 128) cnt0[t] = hist[t];
    __syncthreads();
    for (int off = 1; off < 128; off <<= 1) {  // inclusive scan
        int v = 0;
        if (t < 128 && t >= off) v = hist[t - off];
        __syncthreads();
        if (t < 128) hist[t] += v;
        __syncthreads();
    }
    if (t < 128) {
        int ex = hist[t] - cnt0[t];  // exclusive
        cur[t] = ex;
        if (t < nr) {
            rowptr[d0 + t] = segbase + ex;
            dinv[d0 + t] = rsqrtf((float)(cnt0[t] + 1));  // +1 self-loop
        }
    }
    __syncthreads();
    {
        int j = segbase + t;
        for (; j + 3 * 256 < segend; j += 4 * 256) {
            int v[4], pos[4];
#pragma unroll
            for (int u = 0; u < 4; ++u) v[u] = buck[j + u * 256];
#pragma unroll
            for (int u = 0; u < 4; ++u) pos[u] = atomicAdd(&cur[v[u] >> 17], 1);
#pragma unroll
            for (int u = 0; u < 4; ++u) colx[segbase + pos[u]] = v[u] & 0x1FFFF;
        }
        for (; j < segend; j += 256) {
            int v = buck[j];
            int pos = segbase + atomicAdd(&cur[v >> 17], 1);
            colx[pos] = v & 0x1FFFF;
        }
    }
}

// ------- MFMA GEMM: G = f16( dinv .* (X @ W) ), K=128; X f32 or f16 -------
template <typename XT>
__global__ __launch_bounds__(256) void gemm_mfma(
    const XT* __restrict__ X, const float* __restrict__ W,
    const float* __restrict__ dinv, __half* __restrict__ G, int M, int Ncols) {
    constexpr int BK = 128;
    constexpr int LDP = BK + 8;           // padded stride (f16)
    __shared__ _Float16 xA[64][LDP];      // [row][k]
    __shared__ _Float16 wB[64][LDP];      // [col][k]
    const int t = threadIdx.x;
    const int m0 = blockIdx.x * 64;
    const int c0 = blockIdx.y * 64;

    {
        int r = t & 63, kg = t >> 6;
        int row = m0 + r; if (row >= M) row = M - 1;
        const XT* xr = &X[(size_t)row * BK + kg * 32];
        if constexpr (std::is_same<XT, __half>::value) {
            const uint4* src = (const uint4*)xr;
            uint4* dst = (uint4*)&xA[r][kg * 32];
#pragma unroll
            for (int q = 0; q < 4; ++q) dst[q] = src[q];
        } else {
#pragma unroll
            for (int c = 0; c < 32; c += 8) {
                float4 a = *(const float4*)&xr[c];
                float4 b = *(const float4*)&xr[c + 4];
                half8 h;
                h[0] = (_Float16)a.x; h[1] = (_Float16)a.y;
                h[2] = (_Float16)a.z; h[3] = (_Float16)a.w;
                h[4] = (_Float16)b.x; h[5] = (_Float16)b.y;
                h[6] = (_Float16)b.z; h[7] = (_Float16)b.w;
                *(half8*)&xA[r][kg * 32 + c] = h;
            }
        }
    }
    {
        int cg = t & 15, k0 = t >> 4;
#pragma unroll
        for (int kk = 0; kk < 8; ++kk) {
            int k = k0 + kk * 16;
            float4 wv = *(const float4*)&W[(size_t)k * Ncols + c0 + cg * 4];
            wB[cg * 4 + 0][k] = (_Float16)wv.x;
            wB[cg * 4 + 1][k] = (_Float16)wv.y;
            wB[cg * 4 + 2][k] = (_Float16)wv.z;
            wB[cg * 4 + 3][k] = (_Float16)wv.w;
        }
    }
    __syncthreads();

    const int wv = t >> 6;
    const int lane = t & 63;
    const int fr = lane & 15;
    const int kg8 = (lane >> 4) * 8;
    f32x4 acc0 = {0.f, 0.f, 0.f, 0.f};
    f32x4 acc1 = {0.f, 0.f, 0.f, 0.f};
    f32x4 acc2 = {0.f, 0.f, 0.f, 0.f};
    f32x4 acc3 = {0.f, 0.f, 0.f, 0.f};

#pragma unroll
    for (int ks = 0; ks < BK; ks += 32) {
        half8 af = *(half8*)&xA[wv * 16 + fr][ks + kg8];
        half8 b0 = *(half8*)&wB[0 * 16 + fr][ks + kg8];
        half8 b1 = *(half8*)&wB[1 * 16 + fr][ks + kg8];
        half8 b2 = *(half8*)&wB[2 * 16 + fr][ks + kg8];
        half8 b3 = *(half8*)&wB[3 * 16 + fr][ks + kg8];
        acc0 = __builtin_amdgcn_mfma_f32_16x16x32_f16(af, b0, acc0, 0, 0, 0);
        acc1 = __builtin_amdgcn_mfma_f32_16x16x32_f16(af, b1, acc1, 0, 0, 0);
        acc2 = __builtin_amdgcn_mfma_f32_16x16x32_f16(af, b2, acc2, 0, 0, 0);
        acc3 = __builtin_amdgcn_mfma_f32_16x16x32_f16(af, b3, acc3, 0, 0, 0);
    }

    int r0 = wv * 16 + (lane >> 4) * 4;
    float dv[4];
    bool ok[4];
#pragma unroll
    for (int i = 0; i < 4; ++i) {
        int row = m0 + r0 + i;
        ok[i] = row < M;
        dv[i] = ok[i] ? dinv[row] : 0.f;
    }
    const f32x4* accs[4] = {&acc0, &acc1, &acc2, &acc3};
#pragma unroll
    for (int fc = 0; fc < 4; ++fc) {
        int col = c0 + fc * 16 + fr;
#pragma unroll
        for (int i = 0; i < 4; ++i) {
            if (ok[i]) {
                int row = m0 + r0 + i;
                G[(size_t)row * Ncols + col] = __float2half((*accs[fc])[i] * dv[i]);
            }
        }
    }
}

// ------- agg1 (F=128): single pass, 64 lanes x 1 dword, readlane/SGPR -------
__global__ __launch_bounds__(256) void agg1_full(
    const __half* __restrict__ G, const int* __restrict__ rowptr,
    const int* __restrict__ colx, const float* __restrict__ dinv,
    const float* __restrict__ bias, __half* __restrict__ Out, int N) {
    constexpr int UNR = 16;
    int wid = (int)((blockIdx.x * 256 + threadIdx.x) >> 6);
    int lane = threadIdx.x & 63;
    if (wid >= N) return;
    int s = rowptr[wid], e = rowptr[wid + 1];
    int emain = s + ((e - s) & ~(UNR - 1));

    const unsigned* gp = (const unsigned*)G;          // row = 64 dwords
    unsigned su = gp[((size_t)wid << 6) + lane];      // self term
    __half2 hacc = *(__half2*)&su;
    __half2 hacc2 = __floats2half2_rn(0.f, 0.f);

    for (int j = s; j < emain; j += UNR) {            // exact, unmasked
        int cl = colx[j + (lane & 15)];               // one coalesced load/batch
        unsigned v[UNR];
#pragma unroll
        for (int u = 0; u < UNR; ++u) {
            int cu = __builtin_amdgcn_readlane(cl, u);    // SGPR index
            v[u] = gp[((size_t)cu << 6) + lane];
        }
#pragma unroll
        for (int u = 0; u < UNR; u += 2) {
            hacc  = __hadd2(hacc,  *(__half2*)&v[u]);
            hacc2 = __hadd2(hacc2, *(__half2*)&v[u + 1]);
        }
    }
    if (emain < e) {                                  // one masked batch
        int cl = clampN(colx[min(emain + (lane & 15), e - 1)], N);
        const __half2 one2 = __floats2half2_rn(1.f, 1.f);
        const __half2 zero2 = __floats2half2_rn(0.f, 0.f);
#pragma unroll
        for (int u = 0; u < UNR; ++u) {
            int cu = __builtin_amdgcn_readlane(cl, u);
            unsigned vv = gp[((size_t)cu << 6) + lane];
            __half2 w = (emain + u < e) ? one2 : zero2;
            hacc = __hfma2(w, *(__half2*)&vv, hacc);
        }
    }

    float2 f1 = __half22float2(hacc);
    float2 f2 = __half22float2(hacc2);
    float ax = f1.x + f2.x, ay = f1.y + f2.y;
    float d = dinv[wid];
    float2 bv = *(const float2*)&bias[lane * 2];
    float ox = fmaf(d, ax, bv.x);
    float oy = fmaf(d, ay, bv.y);
    ox = fmaxf(ox, 0.f); oy = fmaxf(oy, 0.f);         // relu (layer 1)
    __half2 h = __floats2half2_rn(ox, oy);
    ((unsigned*)Out)[((size_t)wid << 6) + lane] = *(unsigned*)&h;
}

// ------- agg2 paired (F=64): half-waves take edge pairs; f32 out -------
__global__ __launch_bounds__(256) void agg2_pair(
    const __half* __restrict__ G, const int* __restrict__ rowptr,
    const int* __restrict__ colx, const float* __restrict__ dinv,
    const float* __restrict__ bias, float* __restrict__ Out, int N) {
    constexpr int UNR = 16;
    int wid = (int)((blockIdx.x * 256 + threadIdx.x) >> 6);
    int lane = threadIdx.x & 63;
    if (wid >= N) return;
    int s = rowptr[wid], e = rowptr[wid + 1];
    int emain = s + ((e - s) & ~(UNR - 1));

    const unsigned* gp = (const unsigned*)G;       // row = 32 dwords
    int dw = lane & 31;
    int half = lane >> 5;

    __half2 z = __floats2half2_rn(0.f, 0.f);
    unsigned su = gp[(size_t)wid * 32 + dw];       // self (half 0 only)
    __half2 hacc = half ? z : *(__half2*)&su;
    __half2 hacc2 = z;

    for (int j = s; j < emain; j += UNR) {         // exact, unmasked
        int cl = colx[j + (lane & 15)];
        unsigned v[UNR / 2];
#pragma unroll
        for (int u = 0; u < UNR; u += 2) {
            int c0 = __builtin_amdgcn_readlane(cl, u);
            int c1 = __builtin_amdgcn_readlane(cl, u + 1);
            int cu = half ? c1 : c0;
            v[u / 2] = gp[(size_t)cu * 32 + dw];
        }
#pragma unroll
        for (int u = 0; u < UNR; u += 4) {
            hacc  = __hadd2(hacc,  *(__half2*)&v[u / 2]);
            hacc2 = __hadd2(hacc2, *(__half2*)&v[u / 2 + 1]);
        }
    }
    if (emain < e) {                               // one masked batch
        int cl = clampN(colx[min(emain + (lane & 15), e - 1)], N);
        const __half2 one2 = __floats2half2_rn(1.f, 1.f);
#pragma unroll
        for (int u = 0; u < UNR; u += 2) {
            int c0 = __builtin_amdgcn_readlane(cl, u);
            int c1 = __builtin_amdgcn_readlane(cl, u + 1);
            int cu = half ? c1 : c0;
            unsigned vv = gp[(size_t)cu * 32 + dw];
            int jj = emain + u + half;
            __half2 w = (jj < e) ? one2 : z;
            hacc = __hfma2(w, *(__half2*)&vv, hacc);
        }
    }

    hacc = __hadd2(hacc, hacc2);
    int bits = *(int*)&hacc;
    int other = __shfl_xor(bits, 32, 64);          // cross-half partial
    __half2 ho = *(__half2*)&other;
    float2 f1 = __half22float2(hacc);
    float2 f2 = __half22float2(ho);
    float ax = f1.x + f2.x, ay = f1.y + f2.y;

    if (half == 0) {
        float d = dinv[wid];
        float2 bv = *(const float2*)&bias[dw * 2];
        float2 o;
        o.x = fmaf(d, ax, bv.x);
        o.y = fmaf(d, ay, bv.y);
        *(float2*)&Out[(size_t)wid * 64 + dw * 2] = o;
    }
}

extern "C" void kernel_launch(void* const* d_in, const int* in_sizes, int n_in,
                              void* d_out, int out_size, void* d_ws, size_t ws_size,
                              hipStream_t stream) {
    const float* x  = (const float*)d_in[0];
    const void*  ei = d_in[1];
    const float* w1 = (const float*)d_in[2];
    const float* b1 = (const float*)d_in[3];
    const float* w2 = (const float*)d_in[4];
    const float* b2 = (const float*)d_in[5];
    float* out = (float*)d_out;

    const int N  = in_sizes[0] / 128;   // 100000
    const int E  = in_sizes[1] / 2;     // 3200000
    const int M  = B * KB;              // cnt matrix cells
    const int NR = (N + B - 1) / B;     // nodes per bucket (<=128)

    char* p = (char*)d_ws;
    auto carve = [&](size_t bytes) {
        void* r = (void*)p;
        p += (bytes + 255) & ~(size_t)255;
        return r;
    };
    int*    cnt      = (int*)carve((size_t)M * 4);
    int*    base     = (int*)carve((size_t)M * 4);
    int*    partials = (int*)carve(1024 * 4);
    int*    rowptr   = (int*)carve((size_t)(N + 1) * 4);
    float*  dinv     = (float*)carve((size_t)N * 4);
    int*    colx     = (int*)carve((size_t)E * 4);
    __half* g1       = (__half*)carve((size_t)N * 128 * 2);  // f16 gather table
    __half* a1       = (__half*)carve((size_t)N * 128 * 2);  // f16 h1
    __half* g2       = g1;          // g1 dead after agg1; reuse
    int*    buck     = (int*)a1;    // packed records dead before agg1 writes a1

    const int EPB = (E + KB - 1) / KB;  // edges per K1/K3 block
    const int NBS = M / 256;            // scan blocks (1024)

    bucket_count<<<KB, 1024, 0, stream>>>(ei, E, EPB, NR, cnt, N);
    scan_partials<<<NBS, 256, 0, stream>>>(cnt, partials, M);
    scan_scan<<<1, 1024, 0, stream>>>(partials, NBS);
    scan_write<<<NBS, 256, 0, stream>>>(cnt, partials, base, M);
    bucket_scatter<<<KB, 1024, 0, stream>>>(ei, E, EPB, NR, base, buck, N);
    bucket_csr<<<B, 256, 0, stream>>>(buck, base, E, NR, dinv, rowptr, colx, N);

    // layer 1
    dim3 grid1((N + 63) / 64, 2);
    gemm_mfma<float><<<grid1, 256, 0, stream>>>(x, w1, dinv, g1, N, 128);
    const int aggb = (N + 3) / 4;
    agg1_full<<<aggb, 256, 0, stream>>>(g1, rowptr, colx, dinv, b1, a1, N);

    // layer 2
    dim3 grid2((N + 63) / 64, 1);
    gemm_mfma<__half><<<grid2, 256, 0, stream>>>(a1, w2, dinv, g2, N, 64);
    agg2_pair<<<aggb, 256, 0, stream>>>(g2, rowptr, colx, dinv, b2, out, N);
}